// Round 16
// baseline (128.498 us; speedup 1.0000x reference)
//
#include <hip/hip_runtime.h>

#define TPB 256

typedef float f32x4 __attribute__((ext_vector_type(4)));

// Kernel 1: per-block expert histogram over 256-slot chunks.
__global__ void k_hist(const int* __restrict__ eidx, int* __restrict__ blockHist,
                       int NK, int E) {
    __shared__ int hist[256];
    int tid = threadIdx.x;
    for (int e = tid; e < E; e += TPB) hist[e] = 0;
    __syncthreads();
    int j = blockIdx.x * TPB + tid;
    if (j < NK) atomicAdd(&hist[eidx[j]], 1);
    __syncthreads();
    for (int e = tid; e < E; e += TPB)
        blockHist[(size_t)blockIdx.x * E + e] = hist[e];
}

// Kernel 2: one block per expert — parallel exclusive scan of that expert's
// per-chunk counts (in place); per-expert total -> counts[e]. Serial chains are
// length ceil(numBlocks/TPB)=2 (R8 lesson: long dependent global chains kill).
__global__ void k_scan_blocks(int* __restrict__ blockHist, int* __restrict__ counts,
                              int numBlocks, int E) {
    __shared__ int s[TPB];
    int e = blockIdx.x;
    int tid = threadIdx.x;
    int per = (numBlocks + TPB - 1) / TPB;
    int start = tid * per;
    int end = start + per; if (end > numBlocks) end = numBlocks;
    int sum = 0;
    for (int b = start; b < end; ++b) sum += blockHist[(size_t)b * E + e];
    s[tid] = sum;
    __syncthreads();
    for (int off = 1; off < TPB; off <<= 1) {
        int t = (tid >= off) ? s[tid - off] : 0;
        __syncthreads();
        s[tid] += t;
        __syncthreads();
    }
    int run = (tid == 0) ? 0 : s[tid - 1];
    if (tid == TPB - 1) counts[e] = s[tid];
    for (int b = start; b < end; ++b) {
        size_t idx = (size_t)b * E + e;
        int v = blockHist[idx];
        blockHist[idx] = run;
        run += v;
    }
}

// Kernel 3: FUSED pos + scatter, one block per TOKEN (16384 retire-fast blocks —
// R7/R15 lessons: this geometry is the local optimum; 512 looping blocks and
// 1-wave-per-token both regress). Each block: (a) issue its x-row load first,
// (b) recompute its 256-slot chunk's stable ranks via ballot match-any + LDS
// scans, (c) write its own 8 slots' row_idx/scale, (d) scatter the row.
// A/B this round: PLAIN stores instead of NT (x is read-once now, so L2
// pollution is harmless; fillBuffer hits 6.6 TB/s with plain stores).
__global__ void __launch_bounds__(TPB) k_pos_scatter(
        const int* __restrict__ eidx, const float* __restrict__ scale,
        const int* __restrict__ blockHist, const int* __restrict__ counts,
        const float* __restrict__ x,
        float* __restrict__ row_idx_out, float* __restrict__ scale_out,
        float* __restrict__ cumsum_out, float* __restrict__ out_x,
        int NK, int E, int K, int H) {
    __shared__ int whist[4 * 256];
    __shared__ int wbase[4 * 256];
    __shared__ int cnt_sh[256];
    __shared__ int inc_sh[256];
    __shared__ int pos_sh[TPB];
    int tid  = threadIdx.x;
    int tok  = blockIdx.x;
    int tpc  = TPB / K;                    // tokens per 256-slot chunk
    int chunk = tok / tpc;
    int j    = chunk * TPB + tid;          // flat slot this thread ranks
    int wv   = tid >> 6;
    int lane = tid & 63;

    // (a) issue x-row load early; rank compute hides the HBM latency
    const f32x4* xs = (const f32x4*)(x + (size_t)tok * H);
    int n4 = H >> 2;
    f32x4 v0;
    bool have0 = (tid < n4);
    if (have0) v0 = xs[tid];

    for (int i = tid; i < 4 * E; i += TPB) whist[i] = 0;
    if (tid < E) { int c = counts[tid]; cnt_sh[tid] = c; inc_sh[tid] = c; }
    __syncthreads();

    // inclusive scan of counts over E elements (E <= 256)
    for (int off = 1; off < E; off <<= 1) {
        int v = 0;
        if (tid < E && tid >= off) v = inc_sh[tid - off];
        __syncthreads();
        if (tid < E) inc_sh[tid] += v;
        __syncthreads();
    }
    if (blockIdx.x == 0 && tid < E) cumsum_out[tid] = (float)inc_sh[tid];

    bool valid = (j < NK);
    int e = valid ? eidx[j] : 0;

    // match-any over the wave: mask of lanes with equal e (E <= 256 -> 8 bits)
    unsigned long long mask = __ballot(valid);
    #pragma unroll
    for (int b = 0; b < 8; ++b) {
        unsigned long long bal = __ballot((e >> b) & 1);
        mask &= ((e >> b) & 1) ? bal : ~bal;
    }
    unsigned long long lt = (1ULL << lane) - 1ULL;
    int rank_in_wave = (int)__popcll(mask & lt);
    bool leader = valid && ((mask & lt) == 0);
    if (leader) whist[wv * E + e] = (int)__popcll(mask);
    __syncthreads();

    for (int ee = tid; ee < E; ee += TPB) {
        int base = 0;
        #pragma unroll
        for (int w = 0; w < 4; ++w) {
            wbase[w * E + ee] = base;
            base += whist[w * E + ee];
        }
    }
    __syncthreads();

    if (valid) {
        int off_e = inc_sh[e] - cnt_sh[e];   // exclusive cross-expert offset
        pos_sh[tid] = off_e + blockHist[(size_t)chunk * E + e]
                    + wbase[wv * E + e] + rank_in_wave;
    }
    __syncthreads();

    // (c) this block owns slots [s0, s0+K) of the chunk — write row_idx/scale
    int s0 = (tok - chunk * tpc) * K;
    if (tid < K) {
        int jj = chunk * TPB + s0 + tid;
        if (jj < NK) {
            int p = pos_sh[s0 + tid];
            row_idx_out[jj] = (float)p;
            scale_out[p] = scale[tok];
        }
    }

    // (d) scatter: plain loads (R10: NT loads cost +15us), PLAIN stores (A/B vs
    // R14's NT stores — fillBuffer's 6.6 TB/s uses plain stores).
    if ((size_t)tok * K < (size_t)NK) {
        for (int t = tid; t < n4; t += TPB) {
            f32x4 v = (t == tid) ? v0 : xs[t];
            #pragma unroll
            for (int k = 0; k < 8; ++k) {   // K == 8 here; guard keeps generality
                if (k < K) {
                    f32x4* od = (f32x4*)(out_x + (size_t)pos_sh[s0 + k] * H);
                    od[t] = v;
                }
            }
        }
    }
}

extern "C" void kernel_launch(void* const* d_in, const int* in_sizes, int n_in,
                              void* d_out, int out_size, void* d_ws, size_t ws_size,
                              hipStream_t stream) {
    const float* x     = (const float*)d_in[0];
    const int*   eidx  = (const int*)d_in[1];
    const float* scale = (const float*)d_in[2];

    const int N  = in_sizes[2];            // scale has N elements
    const int H  = in_sizes[0] / N;        // 1024
    const int K  = in_sizes[1] / N;        // 8
    const int NK = N * K;                  // 131072
    const int E  = out_size - (int)((long long)NK * H) - 2 * NK;   // 64

    const int numBlocks = (NK + TPB - 1) / TPB;  // 512 chunks

    // d_out layout (all float)
    float* out_x     = (float*)d_out;
    float* out_rowix = out_x + (size_t)NK * H;
    float* out_cum   = out_rowix + NK;
    float* out_scale = out_cum + E;

    // d_ws layout
    int* blockHist = (int*)d_ws;                        // numBlocks * E
    int* counts    = blockHist + (size_t)numBlocks * E; // E

    k_hist<<<numBlocks, TPB, 0, stream>>>(eidx, blockHist, NK, E);
    k_scan_blocks<<<E, TPB, 0, stream>>>(blockHist, counts, numBlocks, E);
    k_pos_scatter<<<N, TPB, 0, stream>>>(eidx, scale, blockHist, counts, x,
                                         out_rowix, out_scale, out_cum, out_x,
                                         NK, E, K, H);
}

// Round 17
// 117.798 us; speedup vs baseline: 1.0908x; 1.0908x over previous
//
#include <hip/hip_runtime.h>

#define TPB 256

typedef float f32x4 __attribute__((ext_vector_type(4)));

// Kernel 1: per-block expert histogram over 256-slot chunks.
__global__ void k_hist(const int* __restrict__ eidx, int* __restrict__ blockHist,
                       int NK, int E) {
    __shared__ int hist[256];
    int tid = threadIdx.x;
    for (int e = tid; e < E; e += TPB) hist[e] = 0;
    __syncthreads();
    int j = blockIdx.x * TPB + tid;
    if (j < NK) atomicAdd(&hist[eidx[j]], 1);
    __syncthreads();
    for (int e = tid; e < E; e += TPB)
        blockHist[(size_t)blockIdx.x * E + e] = hist[e];
}

// Kernel 2: one block per expert — parallel exclusive scan of that expert's
// per-chunk counts (in place); per-expert total -> counts[e]. Serial chains are
// length ceil(numBlocks/TPB)=2 (R8 lesson: long dependent global chains kill).
__global__ void k_scan_blocks(int* __restrict__ blockHist, int* __restrict__ counts,
                              int numBlocks, int E) {
    __shared__ int s[TPB];
    int e = blockIdx.x;
    int tid = threadIdx.x;
    int per = (numBlocks + TPB - 1) / TPB;
    int start = tid * per;
    int end = start + per; if (end > numBlocks) end = numBlocks;
    int sum = 0;
    for (int b = start; b < end; ++b) sum += blockHist[(size_t)b * E + e];
    s[tid] = sum;
    __syncthreads();
    for (int off = 1; off < TPB; off <<= 1) {
        int t = (tid >= off) ? s[tid - off] : 0;
        __syncthreads();
        s[tid] += t;
        __syncthreads();
    }
    int run = (tid == 0) ? 0 : s[tid - 1];
    if (tid == TPB - 1) counts[e] = s[tid];
    for (int b = start; b < end; ++b) {
        size_t idx = (size_t)b * E + e;
        int v = blockHist[idx];
        blockHist[idx] = run;
        run += v;
    }
}

// Kernel 3: FUSED pos + scatter, one block per TOKEN (16384 retire-fast blocks —
// R7/R15: this geometry is the local optimum). vs R14: counts-scan is now a
// wave-0 shfl scan (kills 12 barriers; E<=64 fits one wave), blockHist chunk row
// LDS-cached by wave 1 (64 coalesced loads instead of 256 scattered).
// Stores: NT (R16 A/B: plain stores cost +10us via L2 write-allocate).
__global__ void __launch_bounds__(TPB) k_pos_scatter(
        const int* __restrict__ eidx, const float* __restrict__ scale,
        const int* __restrict__ blockHist, const int* __restrict__ counts,
        const float* __restrict__ x,
        float* __restrict__ row_idx_out, float* __restrict__ scale_out,
        float* __restrict__ cumsum_out, float* __restrict__ out_x,
        int NK, int E, int K, int H) {
    __shared__ int whist[4 * 256];
    __shared__ int wbase[4 * 256];
    __shared__ int cnt_sh[64];
    __shared__ int off_sh[64];   // exclusive cross-expert offset
    __shared__ int bh_sh[64];    // blockHist[chunk][e]
    __shared__ int pos_sh[TPB];
    int tid  = threadIdx.x;
    int tok  = blockIdx.x;
    int tpc  = TPB / K;                    // tokens per 256-slot chunk
    int chunk = tok / tpc;
    int j    = chunk * TPB + tid;          // flat slot this thread ranks
    int wv   = tid >> 6;
    int lane = tid & 63;

    // (a) issue x-row load early; rank compute hides the HBM latency
    const f32x4* xs = (const f32x4*)(x + (size_t)tok * H);
    int n4 = H >> 2;
    f32x4 v0;
    bool have0 = (tid < n4);
    if (have0) v0 = xs[tid];

    for (int i = tid; i < 4 * E; i += TPB) whist[i] = 0;

    // wave 0: shfl inclusive scan of counts over E<=64 -> cnt_sh/off_sh (no barriers)
    if (wv == 0) {
        int cnt = (lane < E) ? counts[lane] : 0;
        int inc = cnt;
        #pragma unroll
        for (int off = 1; off < 64; off <<= 1) {
            int v = __shfl_up(inc, off);
            if (lane >= off) inc += v;
        }
        if (lane < E) {
            cnt_sh[lane] = cnt;
            off_sh[lane] = inc - cnt;
            if (blockIdx.x == 0) cumsum_out[lane] = (float)inc;
        }
    }
    // wave 1: coalesced load of this chunk's blockHist row
    if (wv == 1 && lane < E) bh_sh[lane] = blockHist[(size_t)chunk * E + lane];
    __syncthreads();

    bool valid = (j < NK);
    int e = valid ? eidx[j] : 0;

    // match-any over the wave: mask of lanes with equal e (E <= 256 -> 8 bits)
    unsigned long long mask = __ballot(valid);
    #pragma unroll
    for (int b = 0; b < 8; ++b) {
        unsigned long long bal = __ballot((e >> b) & 1);
        mask &= ((e >> b) & 1) ? bal : ~bal;
    }
    unsigned long long lt = (1ULL << lane) - 1ULL;
    int rank_in_wave = (int)__popcll(mask & lt);
    bool leader = valid && ((mask & lt) == 0);
    if (leader) whist[wv * E + e] = (int)__popcll(mask);
    __syncthreads();

    for (int ee = tid; ee < E; ee += TPB) {
        int base = 0;
        #pragma unroll
        for (int w = 0; w < 4; ++w) {
            wbase[w * E + ee] = base;
            base += whist[w * E + ee];
        }
    }
    __syncthreads();

    if (valid) {
        pos_sh[tid] = off_sh[e] + bh_sh[e]
                    + wbase[wv * E + e] + rank_in_wave;
    }
    __syncthreads();

    // (c) this block owns slots [s0, s0+K) of the chunk — write row_idx/scale
    int s0 = (tok - chunk * tpc) * K;
    if (tid < K) {
        int jj = chunk * TPB + s0 + tid;
        if (jj < NK) {
            int p = pos_sh[s0 + tid];
            row_idx_out[jj] = (float)p;
            scale_out[p] = scale[tok];
        }
    }

    // (d) scatter: plain loads (R10: NT loads +15us), NT stores (R16: plain +10us)
    if ((size_t)tok * K < (size_t)NK) {
        for (int t = tid; t < n4; t += TPB) {
            f32x4 v = (t == tid) ? v0 : xs[t];
            #pragma unroll
            for (int k = 0; k < 8; ++k) {   // K == 8 here; guard keeps generality
                if (k < K) {
                    f32x4* od = (f32x4*)(out_x + (size_t)pos_sh[s0 + k] * H);
                    __builtin_nontemporal_store(v, od + t);
                }
            }
        }
    }
}

extern "C" void kernel_launch(void* const* d_in, const int* in_sizes, int n_in,
                              void* d_out, int out_size, void* d_ws, size_t ws_size,
                              hipStream_t stream) {
    const float* x     = (const float*)d_in[0];
    const int*   eidx  = (const int*)d_in[1];
    const float* scale = (const float*)d_in[2];

    const int N  = in_sizes[2];            // scale has N elements
    const int H  = in_sizes[0] / N;        // 1024
    const int K  = in_sizes[1] / N;        // 8
    const int NK = N * K;                  // 131072
    const int E  = out_size - (int)((long long)NK * H) - 2 * NK;   // 64

    const int numBlocks = (NK + TPB - 1) / TPB;  // 512 chunks

    // d_out layout (all float)
    float* out_x     = (float*)d_out;
    float* out_rowix = out_x + (size_t)NK * H;
    float* out_cum   = out_rowix + NK;
    float* out_scale = out_cum + E;

    // d_ws layout
    int* blockHist = (int*)d_ws;                        // numBlocks * E
    int* counts    = blockHist + (size_t)numBlocks * E; // E

    k_hist<<<numBlocks, TPB, 0, stream>>>(eidx, blockHist, NK, E);
    k_scan_blocks<<<E, TPB, 0, stream>>>(blockHist, counts, numBlocks, E);
    k_pos_scatter<<<N, TPB, 0, stream>>>(eidx, scale, blockHist, counts, x,
                                         out_rowix, out_scale, out_cum, out_x,
                                         NK, E, K, H);
}